// Round 12
// baseline (204.635 us; speedup 1.0000x reference)
//
#include <hip/hip_runtime.h>
#include <math.h>

#define N_VOX 32768
#define N_EMB 8192
#define DIM 64
#define NCHUNK 8
#define CODES_PER_CHUNK (N_EMB / NCHUNK)       // 1024
#define TILES_PER_CHUNK (CODES_PER_CHUNK / 32) // 32
#define NROUND (TILES_PER_CHUNK / 2)           // 16 barrier rounds (2 tiles each)
#define NTILES (N_EMB / 32)                    // 256
#define TILE_BYTES 8192                        // bh[4x1KB] | bl[4x1KB]
#define ROUND_BYTES (2 * TILE_BYTES)           // 16 KB
#define CHUNK_BYTES (TILES_PER_CHUNK * TILE_BYTES)

typedef _Float16 half8 __attribute__((ext_vector_type(8)));
typedef float floatx16 __attribute__((ext_vector_type(16)));

#define FP16_MIN_NORMAL 6.1035156e-5f
#define LO_SCALE 2048.0f

// -------- kernel A: fused esq + B-fragment stream build (validated R9-R11) ---
// 32x32x16 f16 B-frag per K-chunk o: lane l holds code n=l&31, k=o*16+(l>>5)*8+j.
// Tile (32 codes): [bh o=0..3 | bl o=0..3]; c0arr[code] = -1024*esq.
__global__ __launch_bounds__(64) void cbprep_kernel(const float* __restrict__ cb,
                                                    char* __restrict__ stream,
                                                    float* __restrict__ esq,
                                                    float* __restrict__ c0arr) {
    int l    = threadIdx.x;                      // 0..63
    int m    = l & 31;
    int kg   = l >> 5;
    int tile = blockIdx.x;                       // 0..255
    char* tbase = stream + (size_t)tile * TILE_BYTES;
    int code = tile * 32 + m;

    float ss = 0.f;
    #pragma unroll
    for (int o = 0; o < 4; ++o) {
        const float* p = cb + (size_t)code * DIM + o * 16 + kg * 8;
        half8 h, lo;
        #pragma unroll
        for (int j = 0; j < 8; ++j) {
            float x = p[j];
            ss = fmaf(x, x, ss);
            _Float16 hi = (_Float16)x;
            float hf = (float)hi;
            if (fabsf(hf) < FP16_MIN_NORMAL) { hi = (_Float16)0.f; hf = 0.f; }
            h[j]  = hi;
            lo[j] = (_Float16)((x - hf) * LO_SCALE);
        }
        *(half8*)(tbase +        o * 1024 + l * 16) = h;
        *(half8*)(tbase + 4096 + o * 1024 + l * 16) = lo;
    }
    ss += __shfl_xor(ss, 32, 64);                // both half-rows summed
    if (kg == 0) {
        esq[code]   = ss;
        c0arr[code] = -1024.0f * ss;
    }
}

// -------- kernel B: MFMA argmin scan, LDS dbuf, 8 waves, 2 tiles/barrier -----
// Block = 8 waves (512 thr), same chunk. Wave owns 32 rows x one chunk
// (1024 codes). Round: stage 16KB (2 tiles, 2 segs/wave — same per-wave load
// rate as R11) global->LDS dbuf; compute 24 MFMAs; ONE barrier per round
// (16 total vs R11's 32). acc = 2048*(dot - esq/2), A-side scale (zhs exact).
// Maximize, tie -> earlier tile/lower id. Math + mapping = validated R8-R11.
__global__ __launch_bounds__(512) void scan_kernel(const float* __restrict__ z,
                                                   const char* __restrict__ stream,
                                                   const float* __restrict__ c0arr,
                                                   int* __restrict__ cand_idx) {
    __shared__ __align__(16) char lds[2 * ROUND_BYTES];
    int tid   = threadIdx.x;
    int l     = tid & 63;
    int w     = tid >> 6;                        // wave 0..7
    int chunk = blockIdx.x & (NCHUNK - 1);
    int rg    = blockIdx.x >> 3;                 // 0..127, 256 rows per block
    int m     = l & 31;                          // A row in tile / B col (code)
    int kg    = l >> 5;
    int rowBase = rg * 256 + w * 32;             // wave's 32 rows

    // A fragments: zh (unscaled), zl = 2048*res, zhs = 2048*zh (exact shift)
    half8 zh[4], zl[4], zhs[4];
    const float* zrow = z + (size_t)(rowBase + m) * DIM + kg * 8;
    #pragma unroll
    for (int o = 0; o < 4; ++o) {
        const float* p = zrow + o * 16;
        #pragma unroll
        for (int j = 0; j < 8; ++j) {
            float x = p[j];
            _Float16 hi = (_Float16)x;
            float hf = (float)hi;
            if (fabsf(hf) < FP16_MIN_NORMAL) { hi = (_Float16)0.f; hf = 0.f; }
            zh[o][j] = hi;
            zl[o][j] = (_Float16)((x - hf) * LO_SCALE);
        }
        zhs[o] = zh[o] * (_Float16)2048.0f;
    }

    const char*  sbase = stream + (size_t)chunk * CHUNK_BYTES;
    const float* c0p   = c0arr + chunk * CODES_PER_CHUNK;

    float best[16];
    int   bt[16];
    #pragma unroll
    for (int i = 0; i < 16; ++i) { best[i] = -3.4e38f; bt[i] = 0; }

    // stage one 16KB round (2 tiles): wave w issues segs {w, w+8} (1KB each)
#define STAGE(gr, lb)                                                              \
    do {                                                                           \
        _Pragma("unroll")                                                          \
        for (int _s = w; _s < 16; _s += 8) {                                       \
            const char* _g = (gr) + _s * 1024 + l * 16;                            \
            char*       _d = (lb) + _s * 1024 + l * 16;                            \
            __builtin_amdgcn_global_load_lds(                                      \
                (const __attribute__((address_space(1))) void*)_g,                 \
                (__attribute__((address_space(3))) void*)_d, 16, 0, 0);            \
        }                                                                          \
    } while (0)

    // process one tile's fragments from LDS base lb with acc init C0, tile tt
#define PROC(lb, C0, tt)                                                           \
    do {                                                                           \
        half8 _bh[4], _bl[4];                                                      \
        _Pragma("unroll")                                                          \
        for (int _o = 0; _o < 4; ++_o) {                                           \
            _bh[_o] = *(const half8*)((lb) +        _o * 1024 + l * 16);           \
            _bl[_o] = *(const half8*)((lb) + 4096 + _o * 1024 + l * 16);           \
        }                                                                          \
        floatx16 _acc;                                                             \
        _Pragma("unroll")                                                          \
        for (int _i = 0; _i < 16; ++_i) _acc[_i] = (C0);                           \
        _Pragma("unroll")                                                          \
        for (int _o = 0; _o < 4; ++_o) {                                           \
            _acc = __builtin_amdgcn_mfma_f32_32x32x16_f16(zhs[_o], _bh[_o], _acc, 0, 0, 0); \
            _acc = __builtin_amdgcn_mfma_f32_32x32x16_f16(zl[_o],  _bh[_o], _acc, 0, 0, 0); \
            _acc = __builtin_amdgcn_mfma_f32_32x32x16_f16(zh[_o],  _bl[_o], _acc, 0, 0, 0); \
        }                                                                          \
        _Pragma("unroll")                                                          \
        for (int _i = 0; _i < 16; ++_i)                                            \
            if (_acc[_i] > best[_i]) { best[_i] = _acc[_i]; bt[_i] = (tt); }       \
    } while (0)

    STAGE(sbase, lds);                           // round 0 -> buf 0
    float c0a = c0p[m];                          // tile 0
    float c0b = c0p[32 + m];                     // tile 1
    __syncthreads();                             // staging complete

    for (int r = 0; r < NROUND; ++r) {
        if (r + 1 < NROUND)
            STAGE(sbase + (size_t)(r + 1) * ROUND_BYTES, lds + ((r + 1) & 1) * ROUND_BYTES);
        float c0an = (r + 1 < NROUND) ? c0p[(2 * r + 2) * 32 + m] : 0.f;
        float c0bn = (r + 1 < NROUND) ? c0p[(2 * r + 3) * 32 + m] : 0.f;

        const char* lb = lds + (r & 1) * ROUND_BYTES;
        PROC(lb,              c0a, 2 * r);
        PROC(lb + TILE_BYTES, c0b, 2 * r + 1);

        c0a = c0an; c0b = c0bn;
        __syncthreads();   // next round staged; all waves done with buf r&1
    }
#undef STAGE
#undef PROC

    // Cross-lane argmax over the 32 cols (lane bits 0..4); tie -> lower index.
    // kg=0/1 halves hold different rows; both write their own rows (R8 mapping).
    #pragma unroll
    for (int i = 0; i < 16; ++i) {
        float v  = best[i];
        int   id = bt[i] * 32 + m;               // code index within chunk
        #pragma unroll
        for (int off = 1; off < 32; off <<= 1) {
            float ov = __shfl_xor(v, off, 64);
            int   oi = __shfl_xor(id, off, 64);
            if (ov > v || (ov == v && oi < id)) { v = ov; id = oi; }
        }
        if (m == 0) {
            int row = rowBase + (i & 3) + 8 * (i >> 2) + 4 * kg;
            cand_idx[chunk * N_VOX + row] = chunk * CODES_PER_CHUNK + id;
        }
    }
}

// -------- kernel C: exact fp32 re-score, wave per row (validated R7-R11) -----
// 64 lanes = 8 candidates x 8 dim-segments. Shuffle-tree dot; cross-candidate
// min with id tie-break (ids ascend with chunk -> first occurrence).
__global__ __launch_bounds__(256) void finalize_kernel(const float* __restrict__ z,
                                                       const float* __restrict__ cb,
                                                       const float* __restrict__ esq,
                                                       const int* __restrict__ cand_idx,
                                                       float* __restrict__ out,
                                                       float* __restrict__ partials) {
    int tid  = threadIdx.x;
    int l    = tid & 63;
    int w    = tid >> 6;
    int row  = blockIdx.x * 4 + w;
    int c    = l >> 3;                 // candidate 0..7
    int s    = l & 7;                  // dim segment 0..7 (8 floats each)

    int id = cand_idx[c * N_VOX + row];

    const float4* zp = (const float4*)(z  + (size_t)row * DIM + s * 8);
    const float4* ep = (const float4*)(cb + (size_t)id  * DIM + s * 8);
    float4 z0 = zp[0], z1 = zp[1], e0 = ep[0], e1 = ep[1];
    float p = z0.x*e0.x + z0.y*e0.y + z0.z*e0.z + z0.w*e0.w
            + z1.x*e1.x + z1.y*e1.y + z1.z*e1.z + z1.w*e1.w;
    #pragma unroll
    for (int off = 1; off < 8; off <<= 1)
        p += __shfl_xor(p, off, 8);    // full dot in all 8 lanes of the group

    float score = esq[id] - 2.0f * p;
    #pragma unroll
    for (int off = 8; off < 64; off <<= 1) {
        float ov = __shfl_xor(score, off, 64);
        int   oi = __shfl_xor(id, off, 64);
        if (ov < score || (ov == score && oi < id)) { score = ov; id = oi; }
    }
    // all 64 lanes hold the winning id for this row

    if (l == 0)
        out[(size_t)N_VOX * DIM + 2 + row] = (float)id;

    // cooperative gather+write: lane handles element l
    float zv = z[(size_t)row * DIM + l];
    float qv = cb[(size_t)id * DIM + l];
    float d  = qv - zv;
    out[(size_t)row * DIM + l] = zv + d;   // mirrors reference z + (q - z)
    float ss = d * d;
    #pragma unroll
    for (int off = 1; off < 64; off <<= 1)
        ss += __shfl_xor(ss, off, 64);

    __shared__ float red[4];
    if (l == 0) red[w] = ss;
    __syncthreads();
    if (tid == 0)
        partials[blockIdx.x] = (red[0] + red[1]) + (red[2] + red[3]);
}

// -------- kernel D: reduce 8192 partials -> both losses --------
__global__ __launch_bounds__(256) void loss_kernel(const float* __restrict__ partials,
                                                   float* __restrict__ out) {
    float s = 0.f;
    #pragma unroll
    for (int i = 0; i < 32; ++i)
        s += partials[threadIdx.x + i * 256];
    __shared__ float red[256];
    red[threadIdx.x] = s;
    __syncthreads();
    #pragma unroll
    for (int st = 128; st > 0; st >>= 1) {
        if (threadIdx.x < st) red[threadIdx.x] += red[threadIdx.x + st];
        __syncthreads();
    }
    if (threadIdx.x == 0) {
        float mean = red[0] / (float)((size_t)N_VOX * DIM);
        out[(size_t)N_VOX * DIM + 0] = mean;
        out[(size_t)N_VOX * DIM + 1] = mean;
    }
}

extern "C" void kernel_launch(void* const* d_in, const int* in_sizes, int n_in,
                              void* d_out, int out_size, void* d_ws, size_t ws_size,
                              hipStream_t stream) {
    const float* z  = (const float*)d_in[0];   // [32768, 64]
    const float* cb = (const float*)d_in[1];   // [8192, 64]
    float* out = (float*)d_out;

    // ws: stream [2 MB] | esq [32 KB] | c0arr [32 KB] | cand_idx [1 MB] | partials [32 KB]
    char*  bstream  = (char*)d_ws;
    float* esq      = (float*)(bstream + (size_t)NTILES * TILE_BYTES);
    float* c0arr    = esq + N_EMB;
    int*   cand_idx = (int*)(c0arr + N_EMB);
    float* partials = (float*)(cand_idx + (size_t)NCHUNK * N_VOX);

    cbprep_kernel  <<<dim3(NTILES), dim3(64), 0, stream>>>(cb, bstream, esq, c0arr);
    scan_kernel    <<<dim3((N_VOX / 256) * NCHUNK), dim3(512), 0, stream>>>(z, bstream, c0arr, cand_idx);
    finalize_kernel<<<dim3(N_VOX / 4), dim3(256), 0, stream>>>(z, cb, esq, cand_idx, out, partials);
    loss_kernel    <<<1, 256, 0, stream>>>(partials, out);
}

// Round 13
// 178.019 us; speedup vs baseline: 1.1495x; 1.1495x over previous
//
#include <hip/hip_runtime.h>
#include <math.h>

#define N_VOX 32768
#define N_EMB 8192
#define DIM 64
#define NCHUNK 8
#define CODES_PER_CHUNK (N_EMB / NCHUNK)       // 1024
#define TILES_PER_CHUNK (CODES_PER_CHUNK / 32) // 32
#define NTILES (N_EMB / 32)                    // 256
#define TILE_BYTES 8192                        // bh[4x1KB] | bl[4x1KB]
#define CHUNK_BYTES (TILES_PER_CHUNK * TILE_BYTES)

typedef _Float16 half8 __attribute__((ext_vector_type(8)));
typedef float floatx16 __attribute__((ext_vector_type(16)));

#define FP16_MIN_NORMAL 6.1035156e-5f
#define LO_SCALE 2048.0f

// -------- kernel A: fused esq + B-fragment stream build (validated R9-R12) ---
// 32x32x16 f16 B-frag per K-chunk o: lane l holds code n=l&31, k=o*16+(l>>5)*8+j.
// Tile (32 codes): [bh o=0..3 | bl o=0..3]; c0arr[code] = -1024*esq.
__global__ __launch_bounds__(64) void cbprep_kernel(const float* __restrict__ cb,
                                                    char* __restrict__ stream,
                                                    float* __restrict__ c0arr) {
    int l    = threadIdx.x;                      // 0..63
    int m    = l & 31;
    int kg   = l >> 5;
    int tile = blockIdx.x;                       // 0..255
    char* tbase = stream + (size_t)tile * TILE_BYTES;
    int code = tile * 32 + m;

    float ss = 0.f;
    #pragma unroll
    for (int o = 0; o < 4; ++o) {
        const float* p = cb + (size_t)code * DIM + o * 16 + kg * 8;
        half8 h, lo;
        #pragma unroll
        for (int j = 0; j < 8; ++j) {
            float x = p[j];
            ss = fmaf(x, x, ss);
            _Float16 hi = (_Float16)x;
            float hf = (float)hi;
            if (fabsf(hf) < FP16_MIN_NORMAL) { hi = (_Float16)0.f; hf = 0.f; }
            h[j]  = hi;
            lo[j] = (_Float16)((x - hf) * LO_SCALE);
        }
        *(half8*)(tbase +        o * 1024 + l * 16) = h;
        *(half8*)(tbase + 4096 + o * 1024 + l * 16) = lo;
    }
    ss += __shfl_xor(ss, 32, 64);                // both half-rows summed
    if (kg == 0)
        c0arr[code] = -1024.0f * ss;
}

// -------- kernel B: MFMA argmin scan (R11 structure, + winning-score store) --
// Block = 8 waves (512 thr), same chunk. Wave owns 32 rows x one chunk
// (1024 codes, 32 tiles). Per tile: 8KB staged global->LDS (1KB per wave,
// global_load_lds width 16), double-buffered; all 8 waves consume via
// ds_read_b128. acc = 2048*(dot - esq/2), A-side scale (zhs=2048*zh exact).
// Maximize, tie -> earlier tile/lower id. Math + mapping = validated R8-R12.
__global__ __launch_bounds__(512) void scan_kernel(const float* __restrict__ z,
                                                   const char* __restrict__ stream,
                                                   const float* __restrict__ c0arr,
                                                   float* __restrict__ cand_val,
                                                   int* __restrict__ cand_idx) {
    __shared__ __align__(16) char lds[2 * TILE_BYTES];
    int tid   = threadIdx.x;
    int l     = tid & 63;
    int w     = tid >> 6;                        // wave 0..7
    int chunk = blockIdx.x & (NCHUNK - 1);
    int rg    = blockIdx.x >> 3;                 // 0..127, 256 rows per block
    int m     = l & 31;                          // A row in tile / B col (code)
    int kg    = l >> 5;
    int rowBase = rg * 256 + w * 32;             // wave's 32 rows

    // A fragments: zh (unscaled), zl = 2048*res, zhs = 2048*zh (exact shift)
    half8 zh[4], zl[4], zhs[4];
    const float* zrow = z + (size_t)(rowBase + m) * DIM + kg * 8;
    #pragma unroll
    for (int o = 0; o < 4; ++o) {
        const float* p = zrow + o * 16;
        #pragma unroll
        for (int j = 0; j < 8; ++j) {
            float x = p[j];
            _Float16 hi = (_Float16)x;
            float hf = (float)hi;
            if (fabsf(hf) < FP16_MIN_NORMAL) { hi = (_Float16)0.f; hf = 0.f; }
            zh[o][j] = hi;
            zl[o][j] = (_Float16)((x - hf) * LO_SCALE);
        }
        zhs[o] = zh[o] * (_Float16)2048.0f;
    }

    const char*  sbase = stream + (size_t)chunk * CHUNK_BYTES;
    const float* c0p   = c0arr + chunk * CODES_PER_CHUNK;

    float best[16];
    int   bt[16];
    #pragma unroll
    for (int i = 0; i < 16; ++i) { best[i] = -3.4e38f; bt[i] = 0; }

    // stage one 8KB tile: wave w issues seg w (1KB, lane l -> +l*16)
#define STAGE(gt, lb)                                                              \
    do {                                                                           \
        const char* _g = (gt) + w * 1024 + l * 16;                                 \
        char*       _d = (lb) + w * 1024 + l * 16;                                 \
        __builtin_amdgcn_global_load_lds(                                          \
            (const __attribute__((address_space(1))) void*)_g,                     \
            (__attribute__((address_space(3))) void*)_d, 16, 0, 0);                \
    } while (0)

    STAGE(sbase, lds);                           // tile 0 -> buf 0
    float c0 = c0p[m];                           // tile 0's -1024*esq
    __syncthreads();                             // staging complete

    for (int t = 0; t < TILES_PER_CHUNK; ++t) {
        if (t + 1 < TILES_PER_CHUNK)
            STAGE(sbase + (size_t)(t + 1) * TILE_BYTES, lds + ((t + 1) & 1) * TILE_BYTES);
        float c0n = (t + 1 < TILES_PER_CHUNK) ? c0p[(t + 1) * 32 + m] : 0.f;

        const char* lb = lds + (t & 1) * TILE_BYTES;
        half8 bh[4], bl[4];
        #pragma unroll
        for (int o = 0; o < 4; ++o) {
            bh[o] = *(const half8*)(lb +        o * 1024 + l * 16);
            bl[o] = *(const half8*)(lb + 4096 + o * 1024 + l * 16);
        }

        floatx16 acc;
        #pragma unroll
        for (int i = 0; i < 16; ++i) acc[i] = c0;
        #pragma unroll
        for (int o = 0; o < 4; ++o) {
            acc = __builtin_amdgcn_mfma_f32_32x32x16_f16(zhs[o], bh[o], acc, 0, 0, 0);
            acc = __builtin_amdgcn_mfma_f32_32x32x16_f16(zl[o],  bh[o], acc, 0, 0, 0);
            acc = __builtin_amdgcn_mfma_f32_32x32x16_f16(zh[o],  bl[o], acc, 0, 0, 0);
        }
        #pragma unroll
        for (int i = 0; i < 16; ++i)
            if (acc[i] > best[i]) { best[i] = acc[i]; bt[i] = t; }

        c0 = c0n;
        __syncthreads();   // t+1 staging landed; all waves done reading buf t&1
    }
#undef STAGE

    // Cross-lane argmax over the 32 cols (lane bits 0..4); tie -> lower index.
    // kg=0/1 halves hold different rows; both write their own rows (R8 mapping).
    #pragma unroll
    for (int i = 0; i < 16; ++i) {
        float v  = best[i];
        int   id = bt[i] * 32 + m;               // code index within chunk
        #pragma unroll
        for (int off = 1; off < 32; off <<= 1) {
            float ov = __shfl_xor(v, off, 64);
            int   oi = __shfl_xor(id, off, 64);
            if (ov > v || (ov == v && oi < id)) { v = ov; id = oi; }
        }
        if (m == 0) {
            int row = rowBase + (i & 3) + 8 * (i >> 2) + 4 * kg;
            cand_val[chunk * N_VOX + row] = v;   // winning scaled score
            cand_idx[chunk * N_VOX + row] = chunk * CODES_PER_CHUNK + id;
        }
    }
}

// -------- kernel C: pick max stored score + gather (no re-score) -------------
// 8 lanes per row: lane c reads chunk c's (val, idx); width-8 shuffle argmax
// (tie -> lower id) — identical ordering semantics to scan's within-chunk
// reduce, so cross-chunk pick is consistent with the validated pipeline.
__global__ __launch_bounds__(256) void finalize_kernel(const float* __restrict__ z,
                                                       const float* __restrict__ cb,
                                                       const float* __restrict__ cand_val,
                                                       const int* __restrict__ cand_idx,
                                                       float* __restrict__ out,
                                                       float* __restrict__ partials) {
    int g    = blockIdx.x * 256 + threadIdx.x;
    int row  = g >> 3;
    int c    = g & 7;                  // chunk / candidate 0..7

    float v  = cand_val[c * N_VOX + row];
    int   id = cand_idx[c * N_VOX + row];
    #pragma unroll
    for (int off = 1; off < 8; off <<= 1) {
        float ov = __shfl_xor(v, off, 8);
        int   oi = __shfl_xor(id, off, 8);
        if (ov > v || (ov == v && oi < id)) { v = ov; id = oi; }
    }
    // all 8 lanes hold the winning id for this row

    if (c == 0)
        out[(size_t)N_VOX * DIM + 2 + row] = (float)id;

    // cooperative gather+write: lane handles elements [c*8, c*8+8)
    const float4* zp = (const float4*)(z  + (size_t)row * DIM + c * 8);
    const float4* qp = (const float4*)(cb + (size_t)id  * DIM + c * 8);
    float4*       op = (float4*)(out + (size_t)row * DIM + c * 8);
    float ss = 0.f;
    #pragma unroll
    for (int d = 0; d < 2; ++d) {
        float4 zt = zp[d], qt = qp[d];
        float dx = qt.x - zt.x, dy = qt.y - zt.y;
        float dz = qt.z - zt.z, dw = qt.w - zt.w;
        float4 o;
        o.x = zt.x + dx; o.y = zt.y + dy;   // mirrors reference z + (q - z)
        o.z = zt.z + dz; o.w = zt.w + dw;
        op[d] = o;
        ss += dx*dx + dy*dy + dz*dz + dw*dw;
    }

    __shared__ float red[256];
    red[threadIdx.x] = ss;
    __syncthreads();
    #pragma unroll
    for (int s = 128; s > 0; s >>= 1) {
        if (threadIdx.x < s) red[threadIdx.x] += red[threadIdx.x + s];
        __syncthreads();
    }
    if (threadIdx.x == 0) partials[blockIdx.x] = red[0];
}

// -------- kernel D: reduce 1024 partials -> both losses --------
__global__ __launch_bounds__(256) void loss_kernel(const float* __restrict__ partials,
                                                   float* __restrict__ out) {
    __shared__ float red[256];
    red[threadIdx.x] = (partials[threadIdx.x]       + partials[threadIdx.x + 256])
                     + (partials[threadIdx.x + 512] + partials[threadIdx.x + 768]);
    __syncthreads();
    #pragma unroll
    for (int st = 128; st > 0; st >>= 1) {
        if (threadIdx.x < st) red[threadIdx.x] += red[threadIdx.x + st];
        __syncthreads();
    }
    if (threadIdx.x == 0) {
        float mean = red[0] / (float)((size_t)N_VOX * DIM);
        out[(size_t)N_VOX * DIM + 0] = mean;
        out[(size_t)N_VOX * DIM + 1] = mean;
    }
}

extern "C" void kernel_launch(void* const* d_in, const int* in_sizes, int n_in,
                              void* d_out, int out_size, void* d_ws, size_t ws_size,
                              hipStream_t stream) {
    const float* z  = (const float*)d_in[0];   // [32768, 64]
    const float* cb = (const float*)d_in[1];   // [8192, 64]
    float* out = (float*)d_out;

    // ws: stream [2 MB] | c0arr [32 KB] | cand_val [1 MB] | cand_idx [1 MB] | partials [4 KB]
    char*  bstream  = (char*)d_ws;
    float* c0arr    = (float*)(bstream + (size_t)NTILES * TILE_BYTES);
    float* cand_val = c0arr + N_EMB;
    int*   cand_idx = (int*)(cand_val + (size_t)NCHUNK * N_VOX);
    float* partials = (float*)(cand_idx + (size_t)NCHUNK * N_VOX);

    cbprep_kernel  <<<dim3(NTILES), dim3(64), 0, stream>>>(cb, bstream, c0arr);
    scan_kernel    <<<dim3((N_VOX / 256) * NCHUNK), dim3(512), 0, stream>>>(z, bstream, c0arr, cand_val, cand_idx);
    finalize_kernel<<<dim3(N_VOX * 8 / 256), dim3(256), 0, stream>>>(z, cb, cand_val, cand_idx, out, partials);
    loss_kernel    <<<1, 256, 0, stream>>>(partials, out);
}